// Round 1
// baseline (62.184 us; speedup 1.0000x reference)
//
#include <hip/hip_runtime.h>
#include <math.h>

#define DEV_INLINE __device__ __forceinline__

constexpr int DIM = 8;
constexpr int TRI = 36;       // 8*9/2
constexpr int CTXW = 10;
constexpr int NS_ITERS = 14;
#define EPSF 1e-10f

DEV_INLINE constexpr int SI(int i, int j) { return i * (i + 1) / 2 + j; } // i >= j
// symmetric access with compile-time-folded ternary (i,j are unroll constants)
#define SA(a, i, j) ((i) >= (j) ? (a)[SI((i),(j))] : (a)[SI((j),(i))])

// Load embedding row idx, build lower-tri L (diag clamped >= 1e-4), compute
// r = lower-tri(L L^T) with +1e-10 on the diagonal. Returns trace(L L^T + eps I).
DEV_INLINE float token_rho(const float* __restrict__ emb, int idx, float r[TRI]) {
  float p[TRI];
  const float4* row = reinterpret_cast<const float4*>(emb + (size_t)idx * TRI);
  #pragma unroll
  for (int q = 0; q < 9; ++q) {
    float4 v = row[q];
    p[4 * q + 0] = v.x; p[4 * q + 1] = v.y; p[4 * q + 2] = v.z; p[4 * q + 3] = v.w;
  }
  #pragma unroll
  for (int i = 0; i < DIM; ++i) p[SI(i, i)] = fmaxf(p[SI(i, i)], 1e-4f);
  float tr = 0.f;
  #pragma unroll
  for (int i = 0; i < DIM; ++i) {
    #pragma unroll
    for (int j = 0; j <= i; ++j) {
      float s = 0.f;
      #pragma unroll
      for (int k = 0; k <= j; ++k) s = fmaf(p[SI(i, k)], p[SI(j, k)], s);
      if (i == j) { s += EPSF; tr += s; }
      r[SI(i, j)] = s;
    }
  }
  return tr;
}

// In-place coupled Newton-Schulz sqrt of SPD matrix (lower-tri storage),
// eigenvalues must be in (0, 1].  y <- sqrt(y_in).
DEV_INLINE void ns_sqrt(float y[TRI]) {
  float z[TRI];
  #pragma unroll
  for (int u = 0; u < TRI; ++u) z[u] = 0.f;
  #pragma unroll
  for (int i = 0; i < DIM; ++i) z[SI(i, i)] = 1.f;
  #pragma unroll 1
  for (int it = 0; it < NS_ITERS; ++it) {
    // m = 1.5 I - 0.5 * sym(z*y)
    float m[TRI];
    #pragma unroll
    for (int i = 0; i < DIM; ++i) {
      #pragma unroll
      for (int j = 0; j <= i; ++j) {
        float s = 0.f;
        #pragma unroll
        for (int k = 0; k < DIM; ++k) s = fmaf(SA(z, i, k), SA(y, k, j), s);
        m[SI(i, j)] = -0.5f * s;
      }
    }
    #pragma unroll
    for (int i = 0; i < DIM; ++i) m[SI(i, i)] += 1.5f;
    // y' = sym(y*m); z' = sym(m*z)
    float yn[TRI], zn[TRI];
    #pragma unroll
    for (int i = 0; i < DIM; ++i) {
      #pragma unroll
      for (int j = 0; j <= i; ++j) {
        float sy = 0.f, sz = 0.f;
        #pragma unroll
        for (int k = 0; k < DIM; ++k) {
          sy = fmaf(SA(y, i, k), SA(m, k, j), sy);
          sz = fmaf(SA(m, i, k), SA(z, k, j), sz);
        }
        yn[SI(i, j)] = sy;
        zn[SI(i, j)] = sz;
      }
    }
    #pragma unroll
    for (int u = 0; u < TRI; ++u) { y[u] = yn[u]; z[u] = zn[u]; }
  }
}

__global__ void __launch_bounds__(64, 1)
qcbow_loss_kernel(const int* __restrict__ contexts, const int* __restrict__ targets,
                  const float* __restrict__ emb, float* __restrict__ out,
                  int B, float invB) {
  const int b = blockIdx.x * blockDim.x + threadIdx.x;
  float loss = 0.f;
  if (b < B) {
    // ---- context-average density matrix (masked mean over W tokens) ----
    float rho[TRI];
    #pragma unroll
    for (int u = 0; u < TRI; ++u) rho[u] = 0.f;
    float msum = 0.f;
    #pragma unroll 1
    for (int w = 0; w < CTXW; ++w) {
      int idx = contexts[b * CTXW + w];
      if (idx != 0) {
        float r[TRI];
        float tr = token_rho(emb, idx, r);
        float inv = 1.f / (tr + EPSF);
        #pragma unroll
        for (int u = 0; u < TRI; ++u) rho[u] = fmaf(r[u], inv, rho[u]);
        msum += 1.f;
      }
    }
    float rinv = 1.f / (msum + EPSF);
    #pragma unroll
    for (int u = 0; u < TRI; ++u) rho[u] *= rinv;

    // ---- sqrt_rho via NS on rho/tr(rho) ----
    float s1 = 0.f;
    #pragma unroll
    for (int i = 0; i < DIM; ++i) s1 += rho[SI(i, i)];
    float is1 = 1.f / (s1 + 1e-30f);
    #pragma unroll
    for (int u = 0; u < TRI; ++u) rho[u] *= is1;
    ns_sqrt(rho);
    float sq1 = sqrtf(s1);
    #pragma unroll
    for (int u = 0; u < TRI; ++u) rho[u] *= sq1;   // rho := S = sqrt(context_rho)

    // ---- target density sigma ----
    float sg[TRI];
    {
      int t = targets[b];
      float trt = token_rho(emb, t, sg);
      float inv = 1.f / (trt + EPSF);
      #pragma unroll
      for (int u = 0; u < TRI; ++u) sg[u] *= inv;
    }

    // ---- P = S * sigma * S (symmetric) ----
    float U[DIM * DIM];
    #pragma unroll
    for (int i = 0; i < DIM; ++i) {
      #pragma unroll
      for (int k = 0; k < DIM; ++k) {
        float s = 0.f;
        #pragma unroll
        for (int l = 0; l < DIM; ++l) s = fmaf(SA(rho, i, l), SA(sg, l, k), s);
        U[i * DIM + k] = s;
      }
    }
    float Pm[TRI];
    float s2 = 0.f;
    #pragma unroll
    for (int i = 0; i < DIM; ++i) {
      #pragma unroll
      for (int j = 0; j <= i; ++j) {
        float s = 0.f;
        #pragma unroll
        for (int k = 0; k < DIM; ++k) s = fmaf(U[i * DIM + k], SA(rho, k, j), s);
        Pm[SI(i, j)] = s;
        if (i == j) s2 += s;
      }
    }

    // ---- f = (tr sqrt(P))^2 = s2 * tr(sqrt(P/s2))^2 ----
    float is2 = 1.f / (s2 + 1e-30f);
    #pragma unroll
    for (int u = 0; u < TRI; ++u) Pm[u] *= is2;
    ns_sqrt(Pm);
    float trY = 0.f;
    #pragma unroll
    for (int i = 0; i < DIM; ++i) trY += Pm[SI(i, i)];
    float f = s2 * trY * trY;
    f = fminf(fmaxf(f, 0.f), 1.f);
    loss = -logf(fmaxf(f, 1e-8f)) + 0.1f * (1.f - f);
  }
  // wave (64-lane) reduction, one atomic per block
  #pragma unroll
  for (int off = 32; off > 0; off >>= 1) loss += __shfl_down(loss, off);
  if (threadIdx.x == 0) atomicAdd(out, loss * invB);
}

extern "C" void kernel_launch(void* const* d_in, const int* in_sizes, int n_in,
                              void* d_out, int out_size, void* d_ws, size_t ws_size,
                              hipStream_t stream) {
  const int* contexts = (const int*)d_in[0];
  const int* targets  = (const int*)d_in[1];
  const float* emb    = (const float*)d_in[2];
  float* out = (float*)d_out;
  const int B = in_sizes[1];

  hipMemsetAsync(out, 0, sizeof(float), stream);
  const int block = 64;
  const int grid = (B + block - 1) / block;
  qcbow_loss_kernel<<<grid, block, 0, stream>>>(contexts, targets, emb, out, B, 1.0f / (float)B);
}

// Round 2
// 42.544 us; speedup vs baseline: 1.4616x; 1.4616x over previous
//
#include <hip/hip_runtime.h>
#include <math.h>

#define DEV_INLINE __device__ __forceinline__

constexpr int DIM = 8;
constexpr int TRI = 36;       // 8*9/2
constexpr int CTXW = 10;
constexpr int NS_ITERS = 14;
#define EPSF 1e-10f

DEV_INLINE constexpr int SI(int i, int j) { return i * (i + 1) / 2 + j; } // i >= j
// symmetric access with compile-time-folded ternary (i,j are unroll constants)
#define SA(a, i, j) ((i) >= (j) ? (a)[SI((i),(j))] : (a)[SI((j),(i))])

// Load embedding row idx into lower-tri p with diag clamped >= 1e-4.
DEV_INLINE void load_L(const float* __restrict__ emb, int idx, float p[TRI]) {
  const float4* row = reinterpret_cast<const float4*>(emb + (size_t)idx * TRI);
  #pragma unroll
  for (int q = 0; q < 9; ++q) {
    float4 v = row[q];
    p[4 * q + 0] = v.x; p[4 * q + 1] = v.y; p[4 * q + 2] = v.z; p[4 * q + 3] = v.w;
  }
  #pragma unroll
  for (int i = 0; i < DIM; ++i) p[SI(i, i)] = fmaxf(p[SI(i, i)], 1e-4f);
}

// r = lower-tri(L L^T) with +1e-10 on the diagonal. Returns trace.
DEV_INLINE float llt(const float p[TRI], float r[TRI]) {
  float tr = 0.f;
  #pragma unroll
  for (int i = 0; i < DIM; ++i) {
    #pragma unroll
    for (int j = 0; j <= i; ++j) {
      float s = 0.f;
      #pragma unroll
      for (int k = 0; k <= j; ++k) s = fmaf(p[SI(i, k)], p[SI(j, k)], s);
      if (i == j) { s += EPSF; tr += s; }
      r[SI(i, j)] = s;
    }
  }
  return tr;
}

// In-place coupled Newton-Schulz sqrt of SPD matrix (lower-tri storage),
// eigenvalues must be in (0, 1].  y <- sqrt(y_in).
DEV_INLINE void ns_sqrt(float y[TRI]) {
  float z[TRI];
  #pragma unroll
  for (int u = 0; u < TRI; ++u) z[u] = 0.f;
  #pragma unroll
  for (int i = 0; i < DIM; ++i) z[SI(i, i)] = 1.f;
  #pragma unroll 1
  for (int it = 0; it < NS_ITERS; ++it) {
    // m = 1.5 I - 0.5 * sym(z*y)
    float m[TRI];
    #pragma unroll
    for (int i = 0; i < DIM; ++i) {
      #pragma unroll
      for (int j = 0; j <= i; ++j) {
        float s = 0.f;
        #pragma unroll
        for (int k = 0; k < DIM; ++k) s = fmaf(SA(z, i, k), SA(y, k, j), s);
        m[SI(i, j)] = -0.5f * s;
      }
    }
    #pragma unroll
    for (int i = 0; i < DIM; ++i) m[SI(i, i)] += 1.5f;
    // y' = sym(y*m); z' = sym(m*z)  (independent -> ILP)
    float yn[TRI], zn[TRI];
    #pragma unroll
    for (int i = 0; i < DIM; ++i) {
      #pragma unroll
      for (int j = 0; j <= i; ++j) {
        float sy = 0.f, sz = 0.f;
        #pragma unroll
        for (int k = 0; k < DIM; ++k) {
          sy = fmaf(SA(y, i, k), SA(m, k, j), sy);
          sz = fmaf(SA(m, i, k), SA(z, k, j), sz);
        }
        yn[SI(i, j)] = sy;
        zn[SI(i, j)] = sz;
      }
    }
    #pragma unroll
    for (int u = 0; u < TRI; ++u) { y[u] = yn[u]; z[u] = zn[u]; }
  }
}

__global__ void __launch_bounds__(64, 1)
qcbow_loss_kernel(const int* __restrict__ contexts, const int* __restrict__ targets,
                  const float* __restrict__ emb, float* __restrict__ out,
                  int B, float invB) {
  const int b = blockIdx.x * blockDim.x + threadIdx.x;
  float loss = 0.f;
  if (b < B) {
    // ---- context-average density matrix rho (masked mean over W tokens) ----
    float rho[TRI];
    #pragma unroll
    for (int u = 0; u < TRI; ++u) rho[u] = 0.f;
    float msum = 0.f;
    #pragma unroll 1
    for (int w = 0; w < CTXW; ++w) {
      int idx = contexts[b * CTXW + w];
      if (idx != 0) {
        float p[TRI], r[TRI];
        load_L(emb, idx, p);
        float tr = llt(p, r);
        float inv = 1.f / (tr + EPSF);
        #pragma unroll
        for (int u = 0; u < TRI; ++u) rho[u] = fmaf(r[u], inv, rho[u]);
        msum += 1.f;
      }
    }
    float rinv = 1.f / (msum + EPSF);
    #pragma unroll
    for (int u = 0; u < TRI; ++u) rho[u] *= rinv;

    // ---- target Cholesky factor T (lower-tri) and tr(sigma_unnorm) ----
    float T[TRI];
    load_L(emb, targets[b], T);
    float trt = 8.f * EPSF + EPSF;   // trace(T T^T + eps I) + EPS denom
    #pragma unroll
    for (int u = 0; u < TRI; ++u) trt = fmaf(T[u], T[u], trt);

    // ---- A = T^T rho T  (symmetric PSD; lam(A)/trt == lam(rho*sigma)) ----
    // W = T^T * rho : W[i][j] = sum_{k>=i} T[k][i] * rho[k][j]
    float Wm[DIM * DIM];
    #pragma unroll
    for (int i = 0; i < DIM; ++i) {
      #pragma unroll
      for (int j = 0; j < DIM; ++j) {
        float s = 0.f;
        #pragma unroll
        for (int k = i; k < DIM; ++k) s = fmaf(T[SI(k, i)], SA(rho, k, j), s);
        Wm[i * DIM + j] = s;
      }
    }
    // A[i][j] (j<=i) = sum_{k>=j} W[i][k] * T[k][j]
    float A[TRI];
    float trA = 0.f;
    #pragma unroll
    for (int i = 0; i < DIM; ++i) {
      #pragma unroll
      for (int j = 0; j <= i; ++j) {
        float s = 0.f;
        #pragma unroll
        for (int k = j; k < DIM; ++k) s = fmaf(Wm[i * DIM + k], T[SI(k, j)], s);
        A[SI(i, j)] = s;
        if (i == j) trA += s;
      }
    }

    // ---- f = trA * (tr sqrt(A/trA))^2 / trt ----
    float isA = 1.f / (trA + 1e-30f);
    #pragma unroll
    for (int u = 0; u < TRI; ++u) A[u] *= isA;
    ns_sqrt(A);
    float trY = 0.f;
    #pragma unroll
    for (int i = 0; i < DIM; ++i) trY += A[SI(i, i)];
    float f = trA * trY * trY / trt;
    f = fminf(fmaxf(f, 0.f), 1.f);
    loss = -logf(fmaxf(f, 1e-8f)) + 0.1f * (1.f - f);
  }
  // wave (64-lane) reduction, one atomic per block
  #pragma unroll
  for (int off = 32; off > 0; off >>= 1) loss += __shfl_down(loss, off);
  if (threadIdx.x == 0) atomicAdd(out, loss * invB);
}

extern "C" void kernel_launch(void* const* d_in, const int* in_sizes, int n_in,
                              void* d_out, int out_size, void* d_ws, size_t ws_size,
                              hipStream_t stream) {
  const int* contexts = (const int*)d_in[0];
  const int* targets  = (const int*)d_in[1];
  const float* emb    = (const float*)d_in[2];
  float* out = (float*)d_out;
  const int B = in_sizes[1];

  hipMemsetAsync(out, 0, sizeof(float), stream);
  const int block = 64;
  const int grid = (B + block - 1) / block;
  qcbow_loss_kernel<<<grid, block, 0, stream>>>(contexts, targets, emb, out, B, 1.0f / (float)B);
}

// Round 3
// 33.194 us; speedup vs baseline: 1.8734x; 1.2817x over previous
//
#include <hip/hip_runtime.h>
#include <math.h>

#define DEV_INLINE __device__ __forceinline__

typedef float v2f __attribute__((ext_vector_type(2)));

constexpr int DIM = 8;
constexpr int TRI = 36;       // 8*9/2
constexpr int CTXW = 10;
#define EPSF 1e-10f

DEV_INLINE constexpr int SI(int i, int j) { return i * (i + 1) / 2 + j; } // i >= j
// symmetric access with compile-time-folded ternary (i,j are unroll constants)
#define SA(a, i, j) ((i) >= (j) ? (a)[SI((i),(j))] : (a)[SI((j),(i))])

DEV_INLINE v2f sp2(float s) { return (v2f){s, s}; }

// element (i,j) of full symmetric matrix stored as 8 rows x 4 float2 pairs
#define EL(A, i, j) (A[i][(j) >> 1][(j) & 1])

// fill elements (i,j), j > (i|1), from (j,i)  (24 movs)
DEV_INLINE void mirror(v2f C[DIM][4]) {
  #pragma unroll
  for (int i = 0; i < DIM; ++i)
    #pragma unroll
    for (int j = (i | 1) + 1; j < DIM; ++j)
      EL(C, i, j) = EL(C, j, i);
}

// C = A*B for commuting symmetric A,B (result symmetric):
// compute lower pair-columns (j2 <= i>>1), then mirror.  160 pk_fma + 24 mov.
DEV_INLINE void mm_sym(v2f C[DIM][4], const v2f A[DIM][4], const v2f B[DIM][4]) {
  #pragma unroll
  for (int i = 0; i < DIM; ++i) {
    #pragma unroll
    for (int j2 = 0; j2 <= (i >> 1); ++j2) {
      v2f acc = sp2(0.f);
      #pragma unroll
      for (int k = 0; k < DIM; ++k)
        acc = __builtin_elementwise_fma(sp2(EL(A, i, k)), B[k][j2], acc);
      C[i][j2] = acc;
    }
  }
  mirror(C);
}

// M = 1.5 I - 0.5 * (Z*Y)   (Z,Y symmetric commuting)
DEV_INLINE void mk_m(v2f M[DIM][4], const v2f Z[DIM][4], const v2f Y[DIM][4]) {
  #pragma unroll
  for (int i = 0; i < DIM; ++i) {
    #pragma unroll
    for (int j2 = 0; j2 <= (i >> 1); ++j2) {
      v2f acc = sp2(0.f);
      #pragma unroll
      for (int k = 0; k < DIM; ++k)
        acc = __builtin_elementwise_fma(sp2(EL(Z, i, k)), Y[k][j2], acc);
      M[i][j2] = acc * sp2(-0.5f);
    }
    EL(M, i, i) += 1.5f;
  }
  mirror(M);
}

// one coupled-NS step: (Yin,Zin) -> (Yout,Zout)
DEV_INLINE void ns_step(v2f Yout[DIM][4], v2f Zout[DIM][4],
                        const v2f Yin[DIM][4], const v2f Zin[DIM][4]) {
  v2f M[DIM][4];
  mk_m(M, Zin, Yin);
  mm_sym(Yout, Yin, M);
  mm_sym(Zout, M, Zin);
}

// Load embedding row idx into lower-tri p with diag clamped >= 1e-4.
DEV_INLINE void load_L(const float* __restrict__ emb, int idx, float p[TRI]) {
  const float4* row = reinterpret_cast<const float4*>(emb + (size_t)idx * TRI);
  #pragma unroll
  for (int q = 0; q < 9; ++q) {
    float4 v = row[q];
    p[4 * q + 0] = v.x; p[4 * q + 1] = v.y; p[4 * q + 2] = v.z; p[4 * q + 3] = v.w;
  }
  #pragma unroll
  for (int i = 0; i < DIM; ++i) p[SI(i, i)] = fmaxf(p[SI(i, i)], 1e-4f);
}

__global__ void __launch_bounds__(64, 1)
qcbow_loss_kernel(const int* __restrict__ contexts, const int* __restrict__ targets,
                  const float* __restrict__ emb, float* __restrict__ out,
                  int B, float invB) {
  const int b = blockIdx.x * blockDim.x + threadIdx.x;
  float loss = 0.f;
  if (b < B) {
    // ---- prefetch context indices ----
    int idxs[CTXW];
    const int* crow = contexts + b * CTXW;
    #pragma unroll
    for (int w = 0; w < CTXW; ++w) idxs[w] = crow[w];

    // ---- context-average density matrix R (pair storage, lower pairs) ----
    v2f R[DIM][4];
    #pragma unroll
    for (int i = 0; i < DIM; ++i)
      #pragma unroll
      for (int j2 = 0; j2 <= (i >> 1); ++j2) R[i][j2] = sp2(0.f);
    float msum = 0.f;
    #pragma unroll 2
    for (int w = 0; w < CTXW; ++w) {
      int idx = idxs[w];
      if (idx != 0) {
        float p[TRI];
        load_L(emb, idx, p);
        // r = lower-tri(L L^T), trace (+eps per diag)
        float r[TRI];
        float tr = 0.f;
        #pragma unroll
        for (int i = 0; i < DIM; ++i) {
          #pragma unroll
          for (int j = 0; j <= i; ++j) {
            float s = 0.f;
            #pragma unroll
            for (int k = 0; k <= j; ++k) s = fmaf(p[SI(i, k)], p[SI(j, k)], s);
            if (i == j) { s += EPSF; tr += s; }
            r[SI(i, j)] = s;
          }
        }
        float inv = __builtin_amdgcn_rcpf(tr + EPSF);
        #pragma unroll
        for (int i = 0; i < DIM; ++i) {
          #pragma unroll
          for (int j2 = 0; j2 <= (i >> 1); ++j2) {
            v2f pr = (v2f){SA(r, i, 2 * j2), SA(r, i, 2 * j2 + 1)};
            R[i][j2] = __builtin_elementwise_fma(pr, sp2(inv), R[i][j2]);
          }
        }
        msum += 1.f;
      }
    }
    {
      float rinv = __builtin_amdgcn_rcpf(msum + EPSF);
      #pragma unroll
      for (int i = 0; i < DIM; ++i)
        #pragma unroll
        for (int j2 = 0; j2 <= (i >> 1); ++j2) R[i][j2] *= sp2(rinv);
    }
    mirror(R);

    // ---- target Cholesky factor T and tr(sigma_unnorm)+EPS ----
    float T[TRI];
    load_L(emb, targets[b], T);
    float trt = 8.f * EPSF + EPSF;
    #pragma unroll
    for (int u = 0; u < TRI; ++u) trt = fmaf(T[u], T[u], trt);

    // ---- A = T^T R T  (symmetric PSD; lam(A)/trt == lam(rho*sigma)) ----
    // Wm[i][j pair] = sum_{k>=i} T[k][i] * R[k][j pair]
    v2f Wm[DIM][4];
    #pragma unroll
    for (int i = 0; i < DIM; ++i) {
      #pragma unroll
      for (int j2 = 0; j2 < 4; ++j2) {
        v2f acc = sp2(0.f);
        #pragma unroll
        for (int k = i; k < DIM; ++k)
          acc = __builtin_elementwise_fma(sp2(T[SI(k, i)]), R[k][j2], acc);
        Wm[i][j2] = acc;
      }
    }
    // A[i][j] (j<=i) = sum_{k>=j} Wm(i,k) * T[k][j]   (scalar lower-tri)
    float Al[TRI];
    float trA = 0.f;
    #pragma unroll
    for (int i = 0; i < DIM; ++i) {
      #pragma unroll
      for (int j = 0; j <= i; ++j) {
        float s = 0.f;
        #pragma unroll
        for (int k = j; k < DIM; ++k) s = fmaf(EL(Wm, i, k), T[SI(k, j)], s);
        Al[SI(i, j)] = s;
        if (i == j) trA += s;
      }
    }

    // ---- Y0 = A / trA (pair storage) ----
    float isA = __builtin_amdgcn_rcpf(trA + 1e-30f);
    v2f Ya[DIM][4], Za[DIM][4], Yb[DIM][4], Zb[DIM][4];
    #pragma unroll
    for (int i = 0; i < DIM; ++i)
      #pragma unroll
      for (int j2 = 0; j2 <= (i >> 1); ++j2)
        Ya[i][j2] = (v2f){SA(Al, i, 2 * j2), SA(Al, i, 2 * j2 + 1)} * sp2(isA);
    mirror(Ya);

    // ---- NS iteration 1 peeled (Z0 = I): Z1 = 1.5I - 0.5*Y0, Y1 = Y0*Z1 ----
    #pragma unroll
    for (int i = 0; i < DIM; ++i) {
      #pragma unroll
      for (int j2 = 0; j2 <= (i >> 1); ++j2) Za[i][j2] = Ya[i][j2] * sp2(-0.5f);
      EL(Za, i, i) += 1.5f;
    }
    mirror(Za);
    mm_sym(Yb, Ya, Za);              // state: (Yb, Za) = (y1, z1)

    // ---- NS iterations 2..9 (ping-pong, no copies) ----
    #pragma unroll 1
    for (int t = 0; t < 4; ++t) {
      ns_step(Ya, Zb, Yb, Za);
      ns_step(Yb, Za, Ya, Zb);
    }                                 // state: (Yb, Za) = (y9, z9)

    // ---- final: trY = tr(y9 * m10) = <y9, m10>_F ----
    v2f Mf[DIM][4];
    mk_m(Mf, Za, Yb);
    v2f accv = sp2(0.f);
    #pragma unroll
    for (int i = 0; i < DIM; ++i)
      #pragma unroll
      for (int j2 = 0; j2 < 4; ++j2)
        accv = __builtin_elementwise_fma(Yb[i][j2], Mf[i][j2], accv);
    float trY = accv.x + accv.y;

    float f = trA * trY * trY / trt;
    f = fminf(fmaxf(f, 0.f), 1.f);
    loss = -logf(fmaxf(f, 1e-8f)) + 0.1f * (1.f - f);
  }
  // wave (64-lane) reduction, one atomic per block
  #pragma unroll
  for (int off = 32; off > 0; off >>= 1) loss += __shfl_down(loss, off);
  if (threadIdx.x == 0) atomicAdd(out, loss * invB);
}

extern "C" void kernel_launch(void* const* d_in, const int* in_sizes, int n_in,
                              void* d_out, int out_size, void* d_ws, size_t ws_size,
                              hipStream_t stream) {
  const int* contexts = (const int*)d_in[0];
  const int* targets  = (const int*)d_in[1];
  const float* emb    = (const float*)d_in[2];
  float* out = (float*)d_out;
  const int B = in_sizes[1];

  hipMemsetAsync(out, 0, sizeof(float), stream);
  const int block = 64;
  const int grid = (B + block - 1) / block;
  qcbow_loss_kernel<<<grid, block, 0, stream>>>(contexts, targets, emb, out, B, 1.0f / (float)B);
}